// Round 10
// baseline (549.191 us; speedup 1.0000x reference)
//
#include <hip/hip_runtime.h>
#include <hip/hip_bf16.h>

// DMoN pooling, MI355X. B=8, N=4096, C=128, K=64.
//  k_assign : s = softmax(x@W+b) via fp16-split MFMA; writes s (f32) + packed
//             S fragments (fp16 hi only) in MFMA B-layout.
//  k_fused  : heterogeneous grid 640.
//             blocks 0..511  = k_big: Y = adj @ S. Adj staged via 3-deep
//               16 KB LDS ring (48 KB -> 3 blocks/CU, 24 waves); S-fragments
//               double-buffered in NAMED REGISTERS straight from L2 (no
//               arrays/lambda-pointers: R9's scratch-spill bug was arrays
//               crossing asm "memory" clobbers -> 594 MB spill traffic).
//               4-bit XOR swizzle (l&15)<<4 on BOTH stage-source and ds_read
//               (3-bit version left quarter-waves on 8/16 slots -> 5.3M bank
//               conflicts). Counted vmcnt(2) BEFORE the barrier retires
//               exactly [stage(s), frag(s)], leaves stage(s+1) in flight.
//               Epilogue folds oadj_part = S_tile^T @ Y_tile.
//             blocks 512..639 = k_small: partials of ss = S^T S,
//               pooled = S^T X, csize = colsum(S).
//  k_reduce / k_finalize / k_scalars: reduce partials, losses, normalize.
//  deg never materialized: softmax rows sum to 1 => ca = rowsum(oadj_raw).
// All reductions deterministic (fixed-order partials, no FP atomics).

typedef _Float16 f16x8 __attribute__((ext_vector_type(8)));
typedef float f32x4 __attribute__((ext_vector_type(4)));

#define MFMA16(a, b, c) __builtin_amdgcn_mfma_f32_16x16x32_f16((a), (b), (c), 0, 0, 0)

__device__ __forceinline__ void gld_lds16(const void* g, void* l) {
  __builtin_amdgcn_global_load_lds(
      (const __attribute__((address_space(1))) void*)g,
      (__attribute__((address_space(3))) void*)l, 16, 0, 0);
}

template <int NCHUNK>
__device__ __forceinline__ void stage_lds(const void* g, void* lbase, int tid) {
  char* ld = (char*)lbase + (tid >> 6) * 1024;   // wave-uniform base; HW adds lane*16
  const char* gs = (const char*)g + tid * 16;
#pragma unroll
  for (int p = 0; p < NCHUNK; ++p)
    gld_lds16(gs + p * 4096, ld + p * 4096);
}

// ---------------------------------------------------------------- k_assign
__global__ __launch_bounds__(256) void k_assign(
    const float* __restrict__ x, const float* __restrict__ w,
    const float* __restrict__ bias, float* __restrict__ s_out,
    _Float16* __restrict__ sB) {
  __shared__ __align__(16) _Float16 wT[2][64][136];
  __shared__ __align__(16) float sT[64][76];
  const int b = blockIdx.x & 7;
  const int it = blockIdx.x >> 3;
  const int n_base = it * 64;
  const int tid = threadIdx.x;

  for (int idx = tid; idx < 8192; idx += 256) {
    int c = idx >> 6, k = idx & 63;
    float v = w[idx];
    _Float16 h = (_Float16)v;
    wT[0][k][c] = h;
    wT[1][k][c] = (_Float16)(v - (float)h);
  }
  const int l = tid & 63, wv = tid >> 6;
  const int l15 = l & 15, g = l >> 4;
  float bv[4];
#pragma unroll
  for (int ct = 0; ct < 4; ++ct) bv[ct] = bias[ct * 16 + l15];
  __syncthreads();

  f32x4 acc[4];
#pragma unroll
  for (int ct = 0; ct < 4; ++ct) acc[ct] = (f32x4){bv[ct], bv[ct], bv[ct], bv[ct]};

  const float* xrow = x + ((size_t)(b * 4096 + n_base + wv * 16 + l15)) * 128;
#pragma unroll
  for (int cs = 0; cs < 4; ++cs) {
    const int c0 = cs * 32;
    f32x4 r0 = *(const f32x4*)(xrow + c0 + 8 * g);
    f32x4 r1 = *(const f32x4*)(xrow + c0 + 8 * g + 4);
    f16x8 ah, al;
#pragma unroll
    for (int j = 0; j < 4; ++j) {
      float v0 = r0[j]; _Float16 h0 = (_Float16)v0;
      ah[j] = h0; al[j] = (_Float16)(v0 - (float)h0);
      float v1 = r1[j]; _Float16 h1 = (_Float16)v1;
      ah[4 + j] = h1; al[4 + j] = (_Float16)(v1 - (float)h1);
    }
#pragma unroll
    for (int ct = 0; ct < 4; ++ct) {
      f16x8 bh = *(const f16x8*)&wT[0][ct * 16 + l15][c0 + 8 * g];
      f16x8 bl = *(const f16x8*)&wT[1][ct * 16 + l15][c0 + 8 * g];
      acc[ct] = MFMA16(ah, bh, acc[ct]);
      acc[ct] = MFMA16(al, bh, acc[ct]);
      acc[ct] = MFMA16(ah, bl, acc[ct]);
    }
  }

#pragma unroll
  for (int r = 0; r < 4; ++r) {
    float m = fmaxf(fmaxf(acc[0][r], acc[1][r]), fmaxf(acc[2][r], acc[3][r]));
#pragma unroll
    for (int off = 1; off < 16; off <<= 1) m = fmaxf(m, __shfl_xor(m, off, 64));
    float e[4], sum = 0.f;
#pragma unroll
    for (int ct = 0; ct < 4; ++ct) { e[ct] = __expf(acc[ct][r] - m); sum += e[ct]; }
#pragma unroll
    for (int off = 1; off < 16; off <<= 1) sum += __shfl_xor(sum, off, 64);
    float inv = 1.0f / sum;
#pragma unroll
    for (int ct = 0; ct < 4; ++ct) acc[ct][r] = e[ct] * inv;
  }

  const int row_l = wv * 16 + 4 * g;
  float* srow = s_out + ((size_t)(b * 4096 + n_base)) * 64;
#pragma unroll
  for (int r = 0; r < 4; ++r)
#pragma unroll
    for (int ct = 0; ct < 4; ++ct) {
      srow[(size_t)(row_l + r) * 64 + ct * 16 + l15] = acc[ct][r];
      sT[ct * 16 + l15][row_l + r] = acc[ct][r];
    }
  __syncthreads();

  // repack to B-fragment layout (hi only): [ks][ct][lane][8] fp16
  _Float16* dst = sB + (size_t)(b * 64 + it) * 4096;
#pragma unroll
  for (int p = 0; p < 2; ++p) {
    int slot = tid + 256 * p;                 // 0..511
    int ks = slot >> 8, ct = (slot >> 6) & 3, ln = slot & 63;
    int col = ct * 16 + (ln & 15);
    int row0 = ks * 32 + 8 * (ln >> 4);
    f16x8 o;
#pragma unroll
    for (int j = 0; j < 8; ++j) o[j] = (_Float16)sT[col][row0 + j];
    *(f16x8*)(dst + slot * 8) = o;
  }
}

// frag loads / compute as macros on NAMED values (no arrays -> no scratch).
#define FRAGLOAD(s, F0, F1, F2, F3)                    \
  {                                                    \
    const char* fp_ = fb_lane + (size_t)(s) * 8192;    \
    F0 = *(const f16x8*)(fp_);                         \
    F1 = *(const f16x8*)(fp_ + 1024);                  \
    F2 = *(const f16x8*)(fp_ + 4096);                  \
    F3 = *(const f16x8*)(fp_ + 5120);                  \
  }

#define COMPUTEB(buf, F0, F1, F2, F3)                          \
  {                                                            \
    const char* ab_ = pool + (buf) * 16384 + rowbase;          \
    f32x4 lo0 = *(const f32x4*)(ab_ + in0);                    \
    f32x4 hi0 = *(const f32x4*)(ab_ + in1);                    \
    f16x8 af0;                                                 \
    _Pragma("unroll") for (int j = 0; j < 4; ++j) {            \
      af0[j] = (_Float16)lo0[j];                               \
      af0[4 + j] = (_Float16)hi0[j];                           \
    }                                                          \
    acc0 = MFMA16(af0, F0, acc0);                              \
    acc1 = MFMA16(af0, F1, acc1);                              \
    f32x4 lo1 = *(const f32x4*)(ab_ + in2);                    \
    f32x4 hi1 = *(const f32x4*)(ab_ + in3);                    \
    f16x8 af1;                                                 \
    _Pragma("unroll") for (int j = 0; j < 4; ++j) {            \
      af1[j] = (_Float16)lo1[j];                               \
      af1[4 + j] = (_Float16)hi1[j];                           \
    }                                                          \
    acc0 = MFMA16(af1, F2, acc0);                              \
    acc1 = MFMA16(af1, F3, acc1);                              \
  }

// ---------------------------------------------------------------- k_fused
// blocks 0..511: k_big body. blocks 512..639: k_small body (256 active thr).
__global__ __launch_bounds__(512, 6) void k_fused(
    const float* __restrict__ adj, const _Float16* __restrict__ sB,
    const float* __restrict__ s_out, const float* __restrict__ x,
    float* __restrict__ oadj_part, float* __restrict__ ss_part,
    float* __restrict__ p_part, float* __restrict__ csp) {
  __shared__ __align__(16) char pool[49152];   // big: 3 x 16 KB adj ring
  const int tid = threadIdx.x;

  if (blockIdx.x < 512) {
    // ------------------------------ k_big body
    const int b = blockIdx.x & 7;
    const int nt = blockIdx.x >> 3;
    const int n_base = nt * 64;
    const int l = tid & 63, w = tid >> 6;
    const int rt = w & 3, ch = w >> 2;
    const int g = l >> 4;

    const char* sBb = (const char*)(sB + (size_t)b * 64 * 4096);
    // 4-bit pre-swizzled source: col-byte ^= (row&15)<<4 (bits 4..7).
    const char* asrc = (const char*)adj +
        ((size_t)(b * 4096 + n_base + (tid >> 4)) * 4096) * 4 +
        (((tid & 15) * 16) ^ (((tid >> 4) & 15) << 4));
    const size_t CH1 = (size_t)32 * 16384;
    const char* fb_lane = sBb + ch * 2048 + l * 16;  // per-lane frag base

    auto stage = [&](int s, int buf) {
      char* ab = pool + buf * 16384 + w * 1024;
      const char* a0 = asrc + (size_t)s * 256;
      gld_lds16(a0, ab);
      gld_lds16(a0 + CH1, ab + 8192);
    };

    const int rowbase = (rt * 16 + (l & 15)) * 256;
    const int swz = (l & 15) << 4;
    const int in0 = (0 * 128 + g * 32 + 0 * 16) ^ swz;
    const int in1 = (0 * 128 + g * 32 + 1 * 16) ^ swz;
    const int in2 = (1 * 128 + g * 32 + 0 * 16) ^ swz;
    const int in3 = (1 * 128 + g * 32 + 1 * 16) ^ swz;

    f32x4 acc0 = {}, acc1 = {};
    f16x8 Fa0, Fa1, Fa2, Fa3, Fb0, Fb1, Fb2, Fb3;

    // prologue (vmcnt ledger order): S0[2], F0[4], S1[2]
    stage(0, 0);
    FRAGLOAD(0, Fa0, Fa1, Fa2, Fa3);
    stage(1, 1);

    int bufc = 0;
    for (int s = 0; s < 64; s += 2) {
      // even step: retire own [stage(s), frag(s)] BEFORE barrier; leave
      // stage(s+1) flying. Barrier publishes cross-wave.
      asm volatile("s_waitcnt vmcnt(2)" ::: "memory");
      __builtin_amdgcn_sched_barrier(0);
      __builtin_amdgcn_s_barrier();
      FRAGLOAD(s + 1, Fb0, Fb1, Fb2, Fb3);
      { int nb = bufc + 2; if (nb >= 3) nb -= 3; if (s + 2 < 64) stage(s + 2, nb); }
      COMPUTEB(bufc, Fa0, Fa1, Fa2, Fa3);
      bufc = (bufc == 2) ? 0 : bufc + 1;
      // odd step
      if (s + 1 == 63) asm volatile("s_waitcnt vmcnt(0)" ::: "memory");
      else             asm volatile("s_waitcnt vmcnt(2)" ::: "memory");
      __builtin_amdgcn_sched_barrier(0);
      __builtin_amdgcn_s_barrier();
      if (s + 2 < 64) FRAGLOAD(s + 2, Fa0, Fa1, Fa2, Fa3);
      { int nb = bufc + 2; if (nb >= 3) nb -= 3; if (s + 3 < 64) stage(s + 3, nb); }
      COMPUTEB(bufc, Fb0, Fb1, Fb2, Fb3);
      bufc = (bufc == 2) ? 0 : bufc + 1;
    }

    // epilogue: stage s tile (f32) into ring space, Y -> LDS, fold.
    {
      const char* ssrc =
          (const char*)(s_out + (size_t)(b * 4096 + n_base) * 64) + tid * 16;
      gld_lds16(ssrc, pool + 16384 + w * 1024);
      gld_lds16(ssrc + 8192, pool + 16384 + w * 1024 + 8192);
    }
    __syncthreads();   // drains vmcnt: s staged; ring dead

    float* Yl = (float*)pool;
    float* sl = (float*)(pool + 16384);
#pragma unroll
    for (int r = 0; r < 4; ++r) {
      Yl[(rt * 16 + (l >> 4) * 4 + r) * 64 + (ch * 2 + 0) * 16 + (l & 15)] = acc0[r];
      Yl[(rt * 16 + (l >> 4) * 4 + r) * 64 + (ch * 2 + 1) * 16 + (l & 15)] = acc1[r];
    }
    __syncthreads();

    const int kq = tid >> 4, lq = tid & 15;
    f32x4 a2a = {}, a2b = {};
    for (int r = 0; r < 64; ++r) {
      float sA = sl[r * 64 + kq];
      float sC = sl[r * 64 + 32 + kq];
      f32x4 y4 = *(const f32x4*)(Yl + r * 64 + lq * 4);
#pragma unroll
      for (int j = 0; j < 4; ++j) { a2a[j] += sA * y4[j]; a2b[j] += sC * y4[j]; }
    }
    float* op = oadj_part + ((size_t)(b * 64 + nt)) * 4096;
    *(f32x4*)(op + kq * 64 + lq * 4) = a2a;
    *(f32x4*)(op + (kq + 32) * 64 + lq * 4) = a2b;
  } else {
    // ------------------------------ k_small body (256 active threads)
    const int bid2 = blockIdx.x - 512;      // 0..127
    const int b = bid2 & 7;
    const int ch = bid2 >> 3;               // 16 chunks of 256 rows
    const bool act = tid < 256;
    float* sc = (float*)pool;               // 8 KB
    float* xc = (float*)(pool + 8192);      // 16 KB
    float* qc = (float*)(pool + 8192 + 16384);  // 4*64 floats
    const int kq = tid >> 4, cq = tid & 15;
    const int kk = tid & 63, nq = tid >> 6;
    f32x4 ssa[4] = {};
    f32x4 pa[8] = {};
    float csA = 0.f;
    for (int sub = 0; sub < 8; ++sub) {
      if (sub) __syncthreads();
      const int nb = ch * 256 + sub * 32;
      if (act) {
        stage_lds<2>(s_out + ((size_t)(b * 4096 + nb)) * 64, sc, tid);
        stage_lds<4>(x + ((size_t)(b * 4096 + nb)) * 128, xc, tid);
      }
      __syncthreads();
      if (act) {
        for (int n = 0; n < 32; ++n) {
          f32x4 s4 = *(const f32x4*)(sc + n * 64 + kq * 4);
          f32x4 s4b = *(const f32x4*)(sc + n * 64 + cq * 4);
          f32x4 x4a = *(const f32x4*)(xc + n * 128 + cq * 8);
          f32x4 x4b = *(const f32x4*)(xc + n * 128 + cq * 8 + 4);
#pragma unroll
          for (int i = 0; i < 4; ++i) {
#pragma unroll
            for (int j = 0; j < 4; ++j) {
              ssa[i][j] += s4[i] * s4b[j];
              pa[i * 2][j] += s4[i] * x4a[j];
              pa[i * 2 + 1][j] += s4[i] * x4b[j];
            }
          }
        }
        for (int n = nq; n < 32; n += 4) csA += sc[n * 64 + kk];
      }
    }
    if (act) {
      float* sp = ss_part + ((size_t)(b * 16 + ch)) * 4096;
      float* pp = p_part + ((size_t)(b * 16 + ch)) * 8192;
#pragma unroll
      for (int i = 0; i < 4; ++i) {
        *(f32x4*)(sp + (kq * 4 + i) * 64 + cq * 4) = ssa[i];
        *(f32x4*)(pp + (kq * 4 + i) * 128 + cq * 8) = pa[i * 2];
        *(f32x4*)(pp + (kq * 4 + i) * 128 + cq * 8 + 4) = pa[i * 2 + 1];
      }
    }
    __syncthreads();
    if (act) { qc[nq * 64 + kk] = csA; }
    __syncthreads();
    if (tid < 64)
      csp[(size_t)(b * 16 + ch) * 64 + tid] =
          qc[0 * 64 + tid] + qc[1 * 64 + tid] + qc[2 * 64 + tid] + qc[3 * 64 + tid];
  }
}

// ---------------------------------------------------------------- k_reduce
__global__ __launch_bounds__(256) void k_reduce(
    const float* __restrict__ oadj_part, const float* __restrict__ ss_part,
    const float* __restrict__ p_part, float* __restrict__ oadj_raw,
    float* __restrict__ ss_sum, float* __restrict__ out_feat) {
  const int gid = blockIdx.x * 256 + threadIdx.x;
  if (gid < 32768) {
    int b = gid >> 12, e = gid & 4095;
    float s = 0.f;
    for (int t = 0; t < 64; ++t) s += oadj_part[((size_t)(b * 64 + t)) * 4096 + e];
    oadj_raw[gid] = s;
  } else if (gid < 65536) {
    int g2 = gid - 32768, b = g2 >> 12, e = g2 & 4095;
    float s = 0.f;
    for (int t = 0; t < 16; ++t) s += ss_part[((size_t)(b * 16 + t)) * 4096 + e];
    ss_sum[g2] = s;
  } else {
    int g3 = gid - 65536, b = g3 >> 13, e = g3 & 8191;
    float s = 0.f;
    for (int t = 0; t < 16; ++t) s += p_part[((size_t)(b * 16 + t)) * 8192 + e];
    const float scale = 1.0507009873554805f, alpha = 1.6732632423543772f;
    out_feat[g3] = s > 0.f ? scale * s : scale * alpha * (expf(s) - 1.f);
  }
}

// ---------------------------------------------------------------- k_finalize
// ca = rowsum(oadj_raw); 2m = sum(oadj_raw)  (softmax rows sum to 1).
__global__ __launch_bounds__(256) void k_finalize(
    const float* __restrict__ oadj_raw, const float* __restrict__ ss_sum,
    const float* __restrict__ csp, float* __restrict__ out_adj,
    float* __restrict__ loss_part) {
  __shared__ float red[256];
  __shared__ float ca[64], dvec[64], diag[64];
  const int b = blockIdx.x, t = threadIdx.x;
  const float* ob = oadj_raw + b * 4096;
  const float* ssb = ss_sum + b * 4096;

  if (t < 64) {
    const float* orow = ob + t * 64;
    float full = 0.f, nod = 0.f;
    for (int lc = 0; lc < 64; ++lc) {
      float v = orow[lc];
      full += v;
      nod += (lc != t) ? v : 0.f;
    }
    ca[t] = full;
    dvec[t] = sqrtf(nod) + 1e-15f;
    diag[t] = orow[t];
  }
  __syncthreads();

  red[t] = (t < 64) ? ca[t] : 0.f;
  __syncthreads();
  for (int o = 128; o > 0; o >>= 1) { if (t < o) red[t] += red[t + o]; __syncthreads(); }
  const float sm = red[0];
  __syncthreads();

  red[t] = (t < 64) ? (diag[t] - ca[t] * ca[t] / sm) : 0.f;
  __syncthreads();
  for (int o = 128; o > 0; o >>= 1) { if (t < o) red[t] += red[t + o]; __syncthreads(); }
  const float spectral_b = -red[0] / sm;
  __syncthreads();

  float fp = 0.f;
  for (int i = t; i < 4096; i += 256) { float v = ssb[i]; fp += v * v; }
  red[t] = fp; __syncthreads();
  for (int o = 128; o > 0; o >>= 1) { if (t < o) red[t] += red[t + o]; __syncthreads(); }
  const float fro = sqrtf(red[0]);
  __syncthreads();
  float op2 = 0.f;
  for (int i = t; i < 4096; i += 256) {
    float v = ssb[i] / fro - (((i >> 6) == (i & 63)) ? 0.125f : 0.f);
    op2 += v * v;
  }
  red[t] = op2; __syncthreads();
  for (int o = 128; o > 0; o >>= 1) { if (t < o) red[t] += red[t + o]; __syncthreads(); }
  const float ortho_b = sqrtf(red[0]);
  __syncthreads();

  float csize_k = 0.f;
  if (t < 64) {
    for (int ch = 0; ch < 16; ++ch) csize_k += csp[(size_t)(b * 16 + ch) * 64 + t];
  }
  red[t] = (t < 64) ? csize_k * csize_k : 0.f;
  __syncthreads();
  for (int o = 128; o > 0; o >>= 1) { if (t < o) red[t] += red[t + o]; __syncthreads(); }
  const float cluster_b = sqrtf(red[0]) * 8.f / 4096.f - 1.f;
  __syncthreads();

  for (int i = t; i < 4096; i += 256) {
    int kk = i >> 6, lc = i & 63;
    float v = (kk == lc) ? 0.f : ob[i] / (dvec[kk] * dvec[lc]);
    out_adj[(size_t)b * 4096 + i] = v;
  }
  if (t == 0) {
    loss_part[b * 3 + 0] = spectral_b;
    loss_part[b * 3 + 1] = ortho_b;
    loss_part[b * 3 + 2] = cluster_b;
  }
}

__global__ void k_scalars(const float* __restrict__ lp, float* __restrict__ o3) {
  if (threadIdx.x == 0) {
    float s = 0.f, o = 0.f, c = 0.f;
    for (int b = 0; b < 8; ++b) { s += lp[b * 3]; o += lp[b * 3 + 1]; c += lp[b * 3 + 2]; }
    o3[0] = s * 0.125f; o3[1] = o * 0.125f; o3[2] = c * 0.125f;
  }
}

extern "C" void kernel_launch(void* const* d_in, const int* in_sizes, int n_in,
                              void* d_out, int out_size, void* d_ws, size_t ws_size,
                              hipStream_t stream) {
  const float* x = (const float*)d_in[0];
  const float* adj = (const float*)d_in[1];
  const float* w = (const float*)d_in[2];
  const float* bias = (const float*)d_in[3];
  float* out = (float*)d_out;
  float* s_out = out;                       // [8,4096,64]
  float* out_feat = out + 2097152;          // [8,64,128]
  float* out_adj = out + 2162688;           // [8,64,64]
  float* out_sc = out + 2195456;            // 3 scalars

  char* ws = (char*)d_ws;
  _Float16* sB = (_Float16*)ws;                              // 4 MB
  float* oadj_part = (float*)(ws + (8u << 20));              // 8 MB
  float* ss_part = (float*)(ws + (16u << 20));               // 2 MB
  float* p_part = (float*)(ws + (20u << 20));                // 4 MB
  float* oadj_raw = (float*)(ws + (28u << 20) + (128u << 10));
  float* ss_sum = (float*)(ws + (28u << 20) + (256u << 10));
  float* loss_part = (float*)(ws + (28u << 20) + (384u << 10));
  float* csp = (float*)(ws + (28u << 20) + (512u << 10));    // 32 KB

  k_assign<<<dim3(512), dim3(256), 0, stream>>>(x, w, bias, s_out, sB);
  k_fused<<<dim3(640), dim3(512), 0, stream>>>(adj, sB, s_out, x, oadj_part,
                                               ss_part, p_part, csp);
  k_reduce<<<dim3(512), dim3(256), 0, stream>>>(oadj_part, ss_part, p_part,
                                                oadj_raw, ss_sum, out_feat);
  k_finalize<<<dim3(8), dim3(256), 0, stream>>>(oadj_raw, ss_sum, csp,
                                                out_adj, loss_part);
  k_scalars<<<dim3(1), dim3(64), 0, stream>>>(loss_part, out_sc);
}

// Round 11
// 200.318 us; speedup vs baseline: 2.7416x; 2.7416x over previous
//
#include <hip/hip_runtime.h>
#include <hip/hip_bf16.h>

// DMoN pooling, MI355X. B=8, N=4096, C=128, K=64.
//  k_assign : s = softmax(x@W+b) via fp16-split MFMA; writes s (f32) + packed
//             S fragments (fp16 hi only) in MFMA B-layout.
//  k_fused  : heterogeneous grid 640.
//             blocks 0..511  = k_big: Y = adj @ S. Adj staged via 3-deep
//               16 KB LDS ring; S-fragments double-buffered in registers
//               straight from L2. __launch_bounds__(512,4): R9/R10's (512,6)
//               forced a 40-VGPR budget (occupancy steps at 64/128 VGPR) ->
//               594 MB scratch spill; (512,4) caps at 128 VGPR, no spill,
//               2 blocks/CU. 4-bit XOR swizzle (l&15)<<4 on both stage source
//               and ds_read (bank-conflict-free). Counted vmcnt(2) BEFORE the
//               barrier retires exactly [stage(s), frag(s)], leaves
//               stage(s+1) in flight (never 0 mid-loop). Epilogue folds
//               oadj_part = S_tile^T @ Y_tile.
//             blocks 512..639 = k_small: partials of ss = S^T S,
//               pooled = S^T X, csize = colsum(S).
//  k_reduce / k_finalize / k_scalars: reduce partials, losses, normalize.
//  deg never materialized: softmax rows sum to 1 => ca = rowsum(oadj_raw).
// All reductions deterministic (fixed-order partials, no FP atomics).

typedef _Float16 f16x8 __attribute__((ext_vector_type(8)));
typedef float f32x4 __attribute__((ext_vector_type(4)));

#define MFMA16(a, b, c) __builtin_amdgcn_mfma_f32_16x16x32_f16((a), (b), (c), 0, 0, 0)

__device__ __forceinline__ void gld_lds16(const void* g, void* l) {
  __builtin_amdgcn_global_load_lds(
      (const __attribute__((address_space(1))) void*)g,
      (__attribute__((address_space(3))) void*)l, 16, 0, 0);
}

template <int NCHUNK>
__device__ __forceinline__ void stage_lds(const void* g, void* lbase, int tid) {
  char* ld = (char*)lbase + (tid >> 6) * 1024;   // wave-uniform base; HW adds lane*16
  const char* gs = (const char*)g + tid * 16;
#pragma unroll
  for (int p = 0; p < NCHUNK; ++p)
    gld_lds16(gs + p * 4096, ld + p * 4096);
}

// ---------------------------------------------------------------- k_assign
__global__ __launch_bounds__(256) void k_assign(
    const float* __restrict__ x, const float* __restrict__ w,
    const float* __restrict__ bias, float* __restrict__ s_out,
    _Float16* __restrict__ sB) {
  __shared__ __align__(16) _Float16 wT[2][64][136];
  __shared__ __align__(16) float sT[64][76];
  const int b = blockIdx.x & 7;
  const int it = blockIdx.x >> 3;
  const int n_base = it * 64;
  const int tid = threadIdx.x;

  for (int idx = tid; idx < 8192; idx += 256) {
    int c = idx >> 6, k = idx & 63;
    float v = w[idx];
    _Float16 h = (_Float16)v;
    wT[0][k][c] = h;
    wT[1][k][c] = (_Float16)(v - (float)h);
  }
  const int l = tid & 63, wv = tid >> 6;
  const int l15 = l & 15, g = l >> 4;
  float bv[4];
#pragma unroll
  for (int ct = 0; ct < 4; ++ct) bv[ct] = bias[ct * 16 + l15];
  __syncthreads();

  f32x4 acc[4];
#pragma unroll
  for (int ct = 0; ct < 4; ++ct) acc[ct] = (f32x4){bv[ct], bv[ct], bv[ct], bv[ct]};

  const float* xrow = x + ((size_t)(b * 4096 + n_base + wv * 16 + l15)) * 128;
#pragma unroll
  for (int cs = 0; cs < 4; ++cs) {
    const int c0 = cs * 32;
    f32x4 r0 = *(const f32x4*)(xrow + c0 + 8 * g);
    f32x4 r1 = *(const f32x4*)(xrow + c0 + 8 * g + 4);
    f16x8 ah, al;
#pragma unroll
    for (int j = 0; j < 4; ++j) {
      float v0 = r0[j]; _Float16 h0 = (_Float16)v0;
      ah[j] = h0; al[j] = (_Float16)(v0 - (float)h0);
      float v1 = r1[j]; _Float16 h1 = (_Float16)v1;
      ah[4 + j] = h1; al[4 + j] = (_Float16)(v1 - (float)h1);
    }
#pragma unroll
    for (int ct = 0; ct < 4; ++ct) {
      f16x8 bh = *(const f16x8*)&wT[0][ct * 16 + l15][c0 + 8 * g];
      f16x8 bl = *(const f16x8*)&wT[1][ct * 16 + l15][c0 + 8 * g];
      acc[ct] = MFMA16(ah, bh, acc[ct]);
      acc[ct] = MFMA16(al, bh, acc[ct]);
      acc[ct] = MFMA16(ah, bl, acc[ct]);
    }
  }

#pragma unroll
  for (int r = 0; r < 4; ++r) {
    float m = fmaxf(fmaxf(acc[0][r], acc[1][r]), fmaxf(acc[2][r], acc[3][r]));
#pragma unroll
    for (int off = 1; off < 16; off <<= 1) m = fmaxf(m, __shfl_xor(m, off, 64));
    float e[4], sum = 0.f;
#pragma unroll
    for (int ct = 0; ct < 4; ++ct) { e[ct] = __expf(acc[ct][r] - m); sum += e[ct]; }
#pragma unroll
    for (int off = 1; off < 16; off <<= 1) sum += __shfl_xor(sum, off, 64);
    float inv = 1.0f / sum;
#pragma unroll
    for (int ct = 0; ct < 4; ++ct) acc[ct][r] = e[ct] * inv;
  }

  const int row_l = wv * 16 + 4 * g;
  float* srow = s_out + ((size_t)(b * 4096 + n_base)) * 64;
#pragma unroll
  for (int r = 0; r < 4; ++r)
#pragma unroll
    for (int ct = 0; ct < 4; ++ct) {
      srow[(size_t)(row_l + r) * 64 + ct * 16 + l15] = acc[ct][r];
      sT[ct * 16 + l15][row_l + r] = acc[ct][r];
    }
  __syncthreads();

  // repack to B-fragment layout (hi only): [ks][ct][lane][8] fp16
  _Float16* dst = sB + (size_t)(b * 64 + it) * 4096;
#pragma unroll
  for (int p = 0; p < 2; ++p) {
    int slot = tid + 256 * p;                 // 0..511
    int ks = slot >> 8, ct = (slot >> 6) & 3, ln = slot & 63;
    int col = ct * 16 + (ln & 15);
    int row0 = ks * 32 + 8 * (ln >> 4);
    f16x8 o;
#pragma unroll
    for (int j = 0; j < 8; ++j) o[j] = (_Float16)sT[col][row0 + j];
    *(f16x8*)(dst + slot * 8) = o;
  }
}

// frag loads / compute as macros on NAMED values.
#define FRAGLOAD(s, F0, F1, F2, F3)                    \
  {                                                    \
    const char* fp_ = fb_lane + (size_t)(s) * 8192;    \
    F0 = *(const f16x8*)(fp_);                         \
    F1 = *(const f16x8*)(fp_ + 1024);                  \
    F2 = *(const f16x8*)(fp_ + 4096);                  \
    F3 = *(const f16x8*)(fp_ + 5120);                  \
  }

#define COMPUTEB(buf, F0, F1, F2, F3)                          \
  {                                                            \
    const char* ab_ = pool + (buf) * 16384 + rowbase;          \
    f32x4 lo0 = *(const f32x4*)(ab_ + in0);                    \
    f32x4 hi0 = *(const f32x4*)(ab_ + in1);                    \
    f16x8 af0;                                                 \
    _Pragma("unroll") for (int j = 0; j < 4; ++j) {            \
      af0[j] = (_Float16)lo0[j];                               \
      af0[4 + j] = (_Float16)hi0[j];                           \
    }                                                          \
    acc0 = MFMA16(af0, F0, acc0);                              \
    acc1 = MFMA16(af0, F1, acc1);                              \
    f32x4 lo1 = *(const f32x4*)(ab_ + in2);                    \
    f32x4 hi1 = *(const f32x4*)(ab_ + in3);                    \
    f16x8 af1;                                                 \
    _Pragma("unroll") for (int j = 0; j < 4; ++j) {            \
      af1[j] = (_Float16)lo1[j];                               \
      af1[4 + j] = (_Float16)hi1[j];                           \
    }                                                          \
    acc0 = MFMA16(af1, F2, acc0);                              \
    acc1 = MFMA16(af1, F3, acc1);                              \
  }

// ---------------------------------------------------------------- k_fused
// blocks 0..511: k_big body. blocks 512..639: k_small body (256 active thr).
__global__ __launch_bounds__(512, 4) void k_fused(
    const float* __restrict__ adj, const _Float16* __restrict__ sB,
    const float* __restrict__ s_out, const float* __restrict__ x,
    float* __restrict__ oadj_part, float* __restrict__ ss_part,
    float* __restrict__ p_part, float* __restrict__ csp) {
  __shared__ __align__(16) char pool[49152];   // big: 3 x 16 KB adj ring
  const int tid = threadIdx.x;

  if (blockIdx.x < 512) {
    // ------------------------------ k_big body
    const int b = blockIdx.x & 7;
    const int nt = blockIdx.x >> 3;
    const int n_base = nt * 64;
    const int l = tid & 63, w = tid >> 6;
    const int rt = w & 3, ch = w >> 2;
    const int g = l >> 4;

    const char* sBb = (const char*)(sB + (size_t)b * 64 * 4096);
    // 4-bit pre-swizzled source: col-byte ^= (row&15)<<4 (bits 4..7).
    const char* asrc = (const char*)adj +
        ((size_t)(b * 4096 + n_base + (tid >> 4)) * 4096) * 4 +
        (((tid & 15) * 16) ^ (((tid >> 4) & 15) << 4));
    const size_t CH1 = (size_t)32 * 16384;
    const char* fb_lane = sBb + ch * 2048 + l * 16;  // per-lane frag base

    auto stage = [&](int s, int buf) {
      char* ab = pool + buf * 16384 + w * 1024;
      const char* a0 = asrc + (size_t)s * 256;
      gld_lds16(a0, ab);
      gld_lds16(a0 + CH1, ab + 8192);
    };

    const int rowbase = (rt * 16 + (l & 15)) * 256;
    const int swz = (l & 15) << 4;
    const int in0 = (0 * 128 + g * 32 + 0 * 16) ^ swz;
    const int in1 = (0 * 128 + g * 32 + 1 * 16) ^ swz;
    const int in2 = (1 * 128 + g * 32 + 0 * 16) ^ swz;
    const int in3 = (1 * 128 + g * 32 + 1 * 16) ^ swz;

    f32x4 acc0 = {}, acc1 = {};
    f16x8 Fa0, Fa1, Fa2, Fa3, Fb0, Fb1, Fb2, Fb3;

    // prologue (vmcnt ledger order): S0[2], F0[4], S1[2]
    stage(0, 0);
    FRAGLOAD(0, Fa0, Fa1, Fa2, Fa3);
    stage(1, 1);

    int bufc = 0;
    for (int s = 0; s < 64; s += 2) {
      // even step: retire own [stage(s), frag(s)] BEFORE barrier; leave
      // stage(s+1) flying. Barrier publishes cross-wave.
      asm volatile("s_waitcnt vmcnt(2)" ::: "memory");
      __builtin_amdgcn_sched_barrier(0);
      __builtin_amdgcn_s_barrier();
      FRAGLOAD(s + 1, Fb0, Fb1, Fb2, Fb3);
      { int nb = bufc + 2; if (nb >= 3) nb -= 3; if (s + 2 < 64) stage(s + 2, nb); }
      COMPUTEB(bufc, Fa0, Fa1, Fa2, Fa3);
      bufc = (bufc == 2) ? 0 : bufc + 1;
      // odd step
      if (s + 1 == 63) asm volatile("s_waitcnt vmcnt(0)" ::: "memory");
      else             asm volatile("s_waitcnt vmcnt(2)" ::: "memory");
      __builtin_amdgcn_sched_barrier(0);
      __builtin_amdgcn_s_barrier();
      if (s + 2 < 64) FRAGLOAD(s + 2, Fa0, Fa1, Fa2, Fa3);
      { int nb = bufc + 2; if (nb >= 3) nb -= 3; if (s + 3 < 64) stage(s + 3, nb); }
      COMPUTEB(bufc, Fb0, Fb1, Fb2, Fb3);
      bufc = (bufc == 2) ? 0 : bufc + 1;
    }

    // epilogue: stage s tile (f32) into ring space, Y -> LDS, fold.
    {
      const char* ssrc =
          (const char*)(s_out + (size_t)(b * 4096 + n_base) * 64) + tid * 16;
      gld_lds16(ssrc, pool + 16384 + w * 1024);
      gld_lds16(ssrc + 8192, pool + 16384 + w * 1024 + 8192);
    }
    __syncthreads();   // drains vmcnt: s staged; ring dead

    float* Yl = (float*)pool;
    float* sl = (float*)(pool + 16384);
#pragma unroll
    for (int r = 0; r < 4; ++r) {
      Yl[(rt * 16 + (l >> 4) * 4 + r) * 64 + (ch * 2 + 0) * 16 + (l & 15)] = acc0[r];
      Yl[(rt * 16 + (l >> 4) * 4 + r) * 64 + (ch * 2 + 1) * 16 + (l & 15)] = acc1[r];
    }
    __syncthreads();

    const int kq = tid >> 4, lq = tid & 15;
    f32x4 a2a = {}, a2b = {};
    for (int r = 0; r < 64; ++r) {
      float sA = sl[r * 64 + kq];
      float sC = sl[r * 64 + 32 + kq];
      f32x4 y4 = *(const f32x4*)(Yl + r * 64 + lq * 4);
#pragma unroll
      for (int j = 0; j < 4; ++j) { a2a[j] += sA * y4[j]; a2b[j] += sC * y4[j]; }
    }
    float* op = oadj_part + ((size_t)(b * 64 + nt)) * 4096;
    *(f32x4*)(op + kq * 64 + lq * 4) = a2a;
    *(f32x4*)(op + (kq + 32) * 64 + lq * 4) = a2b;
  } else {
    // ------------------------------ k_small body (256 active threads)
    const int bid2 = blockIdx.x - 512;      // 0..127
    const int b = bid2 & 7;
    const int ch = bid2 >> 3;               // 16 chunks of 256 rows
    const bool act = tid < 256;
    float* sc = (float*)pool;               // 8 KB
    float* xc = (float*)(pool + 8192);      // 16 KB
    float* qc = (float*)(pool + 8192 + 16384);  // 4*64 floats
    const int kq = tid >> 4, cq = tid & 15;
    const int kk = tid & 63, nq = tid >> 6;
    f32x4 ssa[4] = {};
    f32x4 pa[8] = {};
    float csA = 0.f;
    for (int sub = 0; sub < 8; ++sub) {
      if (sub) __syncthreads();
      const int nb = ch * 256 + sub * 32;
      if (act) {
        stage_lds<2>(s_out + ((size_t)(b * 4096 + nb)) * 64, sc, tid);
        stage_lds<4>(x + ((size_t)(b * 4096 + nb)) * 128, xc, tid);
      }
      __syncthreads();
      if (act) {
        for (int n = 0; n < 32; ++n) {
          f32x4 s4 = *(const f32x4*)(sc + n * 64 + kq * 4);
          f32x4 s4b = *(const f32x4*)(sc + n * 64 + cq * 4);
          f32x4 x4a = *(const f32x4*)(xc + n * 128 + cq * 8);
          f32x4 x4b = *(const f32x4*)(xc + n * 128 + cq * 8 + 4);
#pragma unroll
          for (int i = 0; i < 4; ++i) {
#pragma unroll
            for (int j = 0; j < 4; ++j) {
              ssa[i][j] += s4[i] * s4b[j];
              pa[i * 2][j] += s4[i] * x4a[j];
              pa[i * 2 + 1][j] += s4[i] * x4b[j];
            }
          }
        }
        for (int n = nq; n < 32; n += 4) csA += sc[n * 64 + kk];
      }
    }
    if (act) {
      float* sp = ss_part + ((size_t)(b * 16 + ch)) * 4096;
      float* pp = p_part + ((size_t)(b * 16 + ch)) * 8192;
#pragma unroll
      for (int i = 0; i < 4; ++i) {
        *(f32x4*)(sp + (kq * 4 + i) * 64 + cq * 4) = ssa[i];
        *(f32x4*)(pp + (kq * 4 + i) * 128 + cq * 8) = pa[i * 2];
        *(f32x4*)(pp + (kq * 4 + i) * 128 + cq * 8 + 4) = pa[i * 2 + 1];
      }
    }
    __syncthreads();
    if (act) { qc[nq * 64 + kk] = csA; }
    __syncthreads();
    if (tid < 64)
      csp[(size_t)(b * 16 + ch) * 64 + tid] =
          qc[0 * 64 + tid] + qc[1 * 64 + tid] + qc[2 * 64 + tid] + qc[3 * 64 + tid];
  }
}

// ---------------------------------------------------------------- k_reduce
__global__ __launch_bounds__(256) void k_reduce(
    const float* __restrict__ oadj_part, const float* __restrict__ ss_part,
    const float* __restrict__ p_part, float* __restrict__ oadj_raw,
    float* __restrict__ ss_sum, float* __restrict__ out_feat) {
  const int gid = blockIdx.x * 256 + threadIdx.x;
  if (gid < 32768) {
    int b = gid >> 12, e = gid & 4095;
    float s = 0.f;
    for (int t = 0; t < 64; ++t) s += oadj_part[((size_t)(b * 64 + t)) * 4096 + e];
    oadj_raw[gid] = s;
  } else if (gid < 65536) {
    int g2 = gid - 32768, b = g2 >> 12, e = g2 & 4095;
    float s = 0.f;
    for (int t = 0; t < 16; ++t) s += ss_part[((size_t)(b * 16 + t)) * 4096 + e];
    ss_sum[g2] = s;
  } else {
    int g3 = gid - 65536, b = g3 >> 13, e = g3 & 8191;
    float s = 0.f;
    for (int t = 0; t < 16; ++t) s += p_part[((size_t)(b * 16 + t)) * 8192 + e];
    const float scale = 1.0507009873554805f, alpha = 1.6732632423543772f;
    out_feat[g3] = s > 0.f ? scale * s : scale * alpha * (expf(s) - 1.f);
  }
}

// ---------------------------------------------------------------- k_finalize
// ca = rowsum(oadj_raw); 2m = sum(oadj_raw)  (softmax rows sum to 1).
__global__ __launch_bounds__(256) void k_finalize(
    const float* __restrict__ oadj_raw, const float* __restrict__ ss_sum,
    const float* __restrict__ csp, float* __restrict__ out_adj,
    float* __restrict__ loss_part) {
  __shared__ float red[256];
  __shared__ float ca[64], dvec[64], diag[64];
  const int b = blockIdx.x, t = threadIdx.x;
  const float* ob = oadj_raw + b * 4096;
  const float* ssb = ss_sum + b * 4096;

  if (t < 64) {
    const float* orow = ob + t * 64;
    float full = 0.f, nod = 0.f;
    for (int lc = 0; lc < 64; ++lc) {
      float v = orow[lc];
      full += v;
      nod += (lc != t) ? v : 0.f;
    }
    ca[t] = full;
    dvec[t] = sqrtf(nod) + 1e-15f;
    diag[t] = orow[t];
  }
  __syncthreads();

  red[t] = (t < 64) ? ca[t] : 0.f;
  __syncthreads();
  for (int o = 128; o > 0; o >>= 1) { if (t < o) red[t] += red[t + o]; __syncthreads(); }
  const float sm = red[0];
  __syncthreads();

  red[t] = (t < 64) ? (diag[t] - ca[t] * ca[t] / sm) : 0.f;
  __syncthreads();
  for (int o = 128; o > 0; o >>= 1) { if (t < o) red[t] += red[t + o]; __syncthreads(); }
  const float spectral_b = -red[0] / sm;
  __syncthreads();

  float fp = 0.f;
  for (int i = t; i < 4096; i += 256) { float v = ssb[i]; fp += v * v; }
  red[t] = fp; __syncthreads();
  for (int o = 128; o > 0; o >>= 1) { if (t < o) red[t] += red[t + o]; __syncthreads(); }
  const float fro = sqrtf(red[0]);
  __syncthreads();
  float op2 = 0.f;
  for (int i = t; i < 4096; i += 256) {
    float v = ssb[i] / fro - (((i >> 6) == (i & 63)) ? 0.125f : 0.f);
    op2 += v * v;
  }
  red[t] = op2; __syncthreads();
  for (int o = 128; o > 0; o >>= 1) { if (t < o) red[t] += red[t + o]; __syncthreads(); }
  const float ortho_b = sqrtf(red[0]);
  __syncthreads();

  float csize_k = 0.f;
  if (t < 64) {
    for (int ch = 0; ch < 16; ++ch) csize_k += csp[(size_t)(b * 16 + ch) * 64 + t];
  }
  red[t] = (t < 64) ? csize_k * csize_k : 0.f;
  __syncthreads();
  for (int o = 128; o > 0; o >>= 1) { if (t < o) red[t] += red[t + o]; __syncthreads(); }
  const float cluster_b = sqrtf(red[0]) * 8.f / 4096.f - 1.f;
  __syncthreads();

  for (int i = t; i < 4096; i += 256) {
    int kk = i >> 6, lc = i & 63;
    float v = (kk == lc) ? 0.f : ob[i] / (dvec[kk] * dvec[lc]);
    out_adj[(size_t)b * 4096 + i] = v;
  }
  if (t == 0) {
    loss_part[b * 3 + 0] = spectral_b;
    loss_part[b * 3 + 1] = ortho_b;
    loss_part[b * 3 + 2] = cluster_b;
  }
}

__global__ void k_scalars(const float* __restrict__ lp, float* __restrict__ o3) {
  if (threadIdx.x == 0) {
    float s = 0.f, o = 0.f, c = 0.f;
    for (int b = 0; b < 8; ++b) { s += lp[b * 3]; o += lp[b * 3 + 1]; c += lp[b * 3 + 2]; }
    o3[0] = s * 0.125f; o3[1] = o * 0.125f; o3[2] = c * 0.125f;
  }
}

extern "C" void kernel_launch(void* const* d_in, const int* in_sizes, int n_in,
                              void* d_out, int out_size, void* d_ws, size_t ws_size,
                              hipStream_t stream) {
  const float* x = (const float*)d_in[0];
  const float* adj = (const float*)d_in[1];
  const float* w = (const float*)d_in[2];
  const float* bias = (const float*)d_in[3];
  float* out = (float*)d_out;
  float* s_out = out;                       // [8,4096,64]
  float* out_feat = out + 2097152;          // [8,64,128]
  float* out_adj = out + 2162688;           // [8,64,64]
  float* out_sc = out + 2195456;            // 3 scalars

  char* ws = (char*)d_ws;
  _Float16* sB = (_Float16*)ws;                              // 4 MB
  float* oadj_part = (float*)(ws + (8u << 20));              // 8 MB
  float* ss_part = (float*)(ws + (16u << 20));               // 2 MB
  float* p_part = (float*)(ws + (20u << 20));                // 4 MB
  float* oadj_raw = (float*)(ws + (28u << 20) + (128u << 10));
  float* ss_sum = (float*)(ws + (28u << 20) + (256u << 10));
  float* loss_part = (float*)(ws + (28u << 20) + (384u << 10));
  float* csp = (float*)(ws + (28u << 20) + (512u << 10));    // 32 KB

  k_assign<<<dim3(512), dim3(256), 0, stream>>>(x, w, bias, s_out, sB);
  k_fused<<<dim3(640), dim3(512), 0, stream>>>(adj, sB, s_out, x, oadj_part,
                                               ss_part, p_part, csp);
  k_reduce<<<dim3(512), dim3(256), 0, stream>>>(oadj_part, ss_part, p_part,
                                                oadj_raw, ss_sum, out_feat);
  k_finalize<<<dim3(8), dim3(256), 0, stream>>>(oadj_raw, ss_sum, csp,
                                                out_adj, loss_part);
  k_scalars<<<dim3(1), dim3(64), 0, stream>>>(loss_part, out_sc);
}

// Round 12
// 179.571 us; speedup vs baseline: 3.0584x; 1.1155x over previous
//
#include <hip/hip_runtime.h>
#include <hip/hip_bf16.h>

// DMoN pooling, MI355X. B=8, N=4096, C=128, K=64.
//  k_assign : s = softmax(x@W+b) via fp16-split MFMA; writes s (f32) + packed
//             S fragments (fp16 hi only) in MFMA B-layout.
//  k_fused  : heterogeneous grid 640, INTERLEAVED: bid%5==4 -> k_small block
//             (128 total, co-resident with big from t=0, no tail), else
//             k_big block (512 total).
//             k_big: Y = adj @ S via T3/T4 staged pipeline (3-deep LDS ring:
//               16KB adj + 8KB frag per step, 72KB pool; counted vmcnt(3)
//               BEFORE the s_barrier -> own stage retired, next stays in
//               flight, never 0 mid-loop). Adj source pre-XOR-swizzled 4-bit
//               (row&15)<<4, consume ds_reads XOR the same -> bank conflicts
//               5.3M -> ~1.1M (R10 measured). Epilogue folds
//               oadj_part = S_tile^T @ Y_tile.
//             k_small: partials of ss = S^T S, pooled = S^T X, csize.
//  k_reduce / k_finalize / k_scalars: reduce partials, losses, normalize.
//  deg never materialized: softmax rows sum to 1 => ca = rowsum(oadj_raw).
// All reductions deterministic (fixed-order partials, no FP atomics).
// Lessons encoded: (512,6) launch bounds => 40-VGPR spill (R9/R10);
// reg-frags per-wave from L2 lose to LDS-staged frags (R11: 200 vs 172).

typedef _Float16 f16x8 __attribute__((ext_vector_type(8)));
typedef float f32x4 __attribute__((ext_vector_type(4)));

#define MFMA16(a, b, c) __builtin_amdgcn_mfma_f32_16x16x32_f16((a), (b), (c), 0, 0, 0)

__device__ __forceinline__ void gld_lds16(const void* g, void* l) {
  __builtin_amdgcn_global_load_lds(
      (const __attribute__((address_space(1))) void*)g,
      (__attribute__((address_space(3))) void*)l, 16, 0, 0);
}

template <int NCHUNK>
__device__ __forceinline__ void stage_lds(const void* g, void* lbase, int tid) {
  char* ld = (char*)lbase + (tid >> 6) * 1024;   // wave-uniform base; HW adds lane*16
  const char* gs = (const char*)g + tid * 16;
#pragma unroll
  for (int p = 0; p < NCHUNK; ++p)
    gld_lds16(gs + p * 4096, ld + p * 4096);
}

// ---------------------------------------------------------------- k_assign
__global__ __launch_bounds__(256) void k_assign(
    const float* __restrict__ x, const float* __restrict__ w,
    const float* __restrict__ bias, float* __restrict__ s_out,
    _Float16* __restrict__ sB) {
  __shared__ __align__(16) _Float16 wT[2][64][136];
  __shared__ __align__(16) float sT[64][76];
  const int b = blockIdx.x & 7;
  const int it = blockIdx.x >> 3;
  const int n_base = it * 64;
  const int tid = threadIdx.x;

  for (int idx = tid; idx < 8192; idx += 256) {
    int c = idx >> 6, k = idx & 63;
    float v = w[idx];
    _Float16 h = (_Float16)v;
    wT[0][k][c] = h;
    wT[1][k][c] = (_Float16)(v - (float)h);
  }
  const int l = tid & 63, wv = tid >> 6;
  const int l15 = l & 15, g = l >> 4;
  float bv[4];
#pragma unroll
  for (int ct = 0; ct < 4; ++ct) bv[ct] = bias[ct * 16 + l15];
  __syncthreads();

  f32x4 acc[4];
#pragma unroll
  for (int ct = 0; ct < 4; ++ct) acc[ct] = (f32x4){bv[ct], bv[ct], bv[ct], bv[ct]};

  const float* xrow = x + ((size_t)(b * 4096 + n_base + wv * 16 + l15)) * 128;
#pragma unroll
  for (int cs = 0; cs < 4; ++cs) {
    const int c0 = cs * 32;
    f32x4 r0 = *(const f32x4*)(xrow + c0 + 8 * g);
    f32x4 r1 = *(const f32x4*)(xrow + c0 + 8 * g + 4);
    f16x8 ah, al;
#pragma unroll
    for (int j = 0; j < 4; ++j) {
      float v0 = r0[j]; _Float16 h0 = (_Float16)v0;
      ah[j] = h0; al[j] = (_Float16)(v0 - (float)h0);
      float v1 = r1[j]; _Float16 h1 = (_Float16)v1;
      ah[4 + j] = h1; al[4 + j] = (_Float16)(v1 - (float)h1);
    }
#pragma unroll
    for (int ct = 0; ct < 4; ++ct) {
      f16x8 bh = *(const f16x8*)&wT[0][ct * 16 + l15][c0 + 8 * g];
      f16x8 bl = *(const f16x8*)&wT[1][ct * 16 + l15][c0 + 8 * g];
      acc[ct] = MFMA16(ah, bh, acc[ct]);
      acc[ct] = MFMA16(al, bh, acc[ct]);
      acc[ct] = MFMA16(ah, bl, acc[ct]);
    }
  }

#pragma unroll
  for (int r = 0; r < 4; ++r) {
    float m = fmaxf(fmaxf(acc[0][r], acc[1][r]), fmaxf(acc[2][r], acc[3][r]));
#pragma unroll
    for (int off = 1; off < 16; off <<= 1) m = fmaxf(m, __shfl_xor(m, off, 64));
    float e[4], sum = 0.f;
#pragma unroll
    for (int ct = 0; ct < 4; ++ct) { e[ct] = __expf(acc[ct][r] - m); sum += e[ct]; }
#pragma unroll
    for (int off = 1; off < 16; off <<= 1) sum += __shfl_xor(sum, off, 64);
    float inv = 1.0f / sum;
#pragma unroll
    for (int ct = 0; ct < 4; ++ct) acc[ct][r] = e[ct] * inv;
  }

  const int row_l = wv * 16 + 4 * g;
  float* srow = s_out + ((size_t)(b * 4096 + n_base)) * 64;
#pragma unroll
  for (int r = 0; r < 4; ++r)
#pragma unroll
    for (int ct = 0; ct < 4; ++ct) {
      srow[(size_t)(row_l + r) * 64 + ct * 16 + l15] = acc[ct][r];
      sT[ct * 16 + l15][row_l + r] = acc[ct][r];
    }
  __syncthreads();

  // repack to B-fragment layout (hi only): [ks][ct][lane][8] fp16
  _Float16* dst = sB + (size_t)(b * 64 + it) * 4096;
#pragma unroll
  for (int p = 0; p < 2; ++p) {
    int slot = tid + 256 * p;                 // 0..511
    int ks = slot >> 8, ct = (slot >> 6) & 3, ln = slot & 63;
    int col = ct * 16 + (ln & 15);
    int row0 = ks * 32 + 8 * (ln >> 4);
    f16x8 o;
#pragma unroll
    for (int j = 0; j < 8; ++j) o[j] = (_Float16)sT[col][row0 + j];
    *(f16x8*)(dst + slot * 8) = o;
  }
}

// ---------------------------------------------------------------- k_fused
// bid%5==4 -> k_small (id bid/5); else k_big (id = (bid/5)*4 + bid%5).
__global__ __launch_bounds__(512, 4) void k_fused(
    const float* __restrict__ adj, const _Float16* __restrict__ sB,
    const float* __restrict__ s_out, const float* __restrict__ x,
    float* __restrict__ oadj_part, float* __restrict__ ss_part,
    float* __restrict__ p_part, float* __restrict__ csp) {
  __shared__ __align__(16) char pool[73728];   // big: 3*16K adj + 3*8K frag
  const int tid = threadIdx.x;
  const int q5 = blockIdx.x / 5, r5 = blockIdx.x % 5;

  if (r5 != 4) {
    // ------------------------------ k_big body (R8 structure, 4-bit swizzle)
    const int big = q5 * 4 + r5;            // 0..511
    const int b = big & 7;
    const int nt = big >> 3;
    const int n_base = nt * 64;
    const int l = tid & 63, w = tid >> 6;
    const int rt = w & 3, ch = w >> 2;
    const int g = l >> 4;

    const char* sBb = (const char*)(sB + (size_t)b * 64 * 4096);
    // 4-bit pre-swizzled source: col-byte ^= (row&15)<<4 (bits 4..7).
    const char* asrc = (const char*)adj +
        ((size_t)(b * 4096 + n_base + (tid >> 4)) * 4096) * 4 +
        (((tid & 15) * 16) ^ (((tid >> 4) & 15) << 4));
    const size_t CH1 = (size_t)32 * 16384;
    const char* fsrc = sBb + tid * 16;

    auto stage = [&](int s, int buf) {
      char* ab = pool + buf * 16384 + w * 1024;
      const char* a0 = asrc + (size_t)s * 256;
      gld_lds16(a0, ab);
      gld_lds16(a0 + CH1, ab + 8192);
      gld_lds16(fsrc + (size_t)s * 8192, pool + 49152 + buf * 8192 + w * 1024);
    };

    stage(0, 0);
    stage(1, 1);

    const int rowbase = (rt * 16 + (l & 15)) * 256;
    const int swz = (l & 15) << 4;
    int innerX[4];
#pragma unroll
    for (int ks = 0; ks < 2; ++ks)
#pragma unroll
      for (int part = 0; part < 2; ++part)
        innerX[ks * 2 + part] = (ks * 128 + g * 32 + part * 16) ^ swz;

    f32x4 acc[2] = {};
    int buf = 0;
    for (int s = 0; s < 64; ++s) {
      // counted wait BEFORE barrier: retire own stage(s) [3 ops], leave
      // stage(s+1) [3 ops] in flight; never vmcnt(0) mid-loop.
      if (s == 63) asm volatile("s_waitcnt vmcnt(0)" ::: "memory");
      else         asm volatile("s_waitcnt vmcnt(3)" ::: "memory");
      __builtin_amdgcn_sched_barrier(0);
      __builtin_amdgcn_s_barrier();
      if (s < 62) {
        int nb = buf + 2; if (nb >= 3) nb -= 3;
        stage(s + 2, nb);
      }
      const char* ab = pool + buf * 16384;
      const char* fbb = pool + 49152 + buf * 8192;
#pragma unroll
      for (int ks = 0; ks < 2; ++ks) {
        f32x4 lo = *(const f32x4*)(ab + rowbase + innerX[ks * 2]);
        f32x4 hi = *(const f32x4*)(ab + rowbase + innerX[ks * 2 + 1]);
        f16x8 af;
#pragma unroll
        for (int j = 0; j < 4; ++j) {
          af[j] = (_Float16)lo[j];
          af[4 + j] = (_Float16)hi[j];
        }
        f16x8 b0 = *(const f16x8*)(fbb + (ks * 4 + ch * 2 + 0) * 1024 + l * 16);
        f16x8 b1 = *(const f16x8*)(fbb + (ks * 4 + ch * 2 + 1) * 1024 + l * 16);
        acc[0] = MFMA16(af, b0, acc[0]);
        acc[1] = MFMA16(af, b1, acc[1]);
      }
      buf = (buf == 2) ? 0 : buf + 1;
    }

    // epilogue: stage s tile (f32) into dead ring space, Y -> LDS, fold.
    {
      const char* ssrc =
          (const char*)(s_out + (size_t)(b * 4096 + n_base) * 64) + tid * 16;
      gld_lds16(ssrc, pool + 16384 + w * 1024);
      gld_lds16(ssrc + 8192, pool + 16384 + w * 1024 + 8192);
    }
    __syncthreads();   // drains vmcnt: s staged; ring dead

    float* Yl = (float*)pool;
    float* sl = (float*)(pool + 16384);
#pragma unroll
    for (int r = 0; r < 4; ++r) {
      Yl[(rt * 16 + (l >> 4) * 4 + r) * 64 + (ch * 2 + 0) * 16 + (l & 15)] = acc[0][r];
      Yl[(rt * 16 + (l >> 4) * 4 + r) * 64 + (ch * 2 + 1) * 16 + (l & 15)] = acc[1][r];
    }
    __syncthreads();

    const int kq = tid >> 4, lq = tid & 15;
    f32x4 a2a = {}, a2b = {};
    for (int r = 0; r < 64; ++r) {
      float sA = sl[r * 64 + kq];
      float sC = sl[r * 64 + 32 + kq];
      f32x4 y4 = *(const f32x4*)(Yl + r * 64 + lq * 4);
#pragma unroll
      for (int j = 0; j < 4; ++j) { a2a[j] += sA * y4[j]; a2b[j] += sC * y4[j]; }
    }
    float* op = oadj_part + ((size_t)(b * 64 + nt)) * 4096;
    *(f32x4*)(op + kq * 64 + lq * 4) = a2a;
    *(f32x4*)(op + (kq + 32) * 64 + lq * 4) = a2b;
  } else {
    // ------------------------------ k_small body (256 active threads)
    const int bid2 = q5;                    // 0..127
    const int b = bid2 & 7;
    const int ch = bid2 >> 3;               // 16 chunks of 256 rows
    const bool act = tid < 256;
    float* sc = (float*)pool;               // 8 KB
    float* xc = (float*)(pool + 8192);      // 16 KB
    float* qc = (float*)(pool + 8192 + 16384);  // 4*64 floats
    const int kq = tid >> 4, cq = tid & 15;
    const int kk = tid & 63, nq = tid >> 6;
    f32x4 ssa[4] = {};
    f32x4 pa[8] = {};
    float csA = 0.f;
    for (int sub = 0; sub < 8; ++sub) {
      if (sub) __syncthreads();
      const int nb = ch * 256 + sub * 32;
      if (act) {
        stage_lds<2>(s_out + ((size_t)(b * 4096 + nb)) * 64, sc, tid);
        stage_lds<4>(x + ((size_t)(b * 4096 + nb)) * 128, xc, tid);
      }
      __syncthreads();
      if (act) {
        for (int n = 0; n < 32; ++n) {
          f32x4 s4 = *(const f32x4*)(sc + n * 64 + kq * 4);
          f32x4 s4b = *(const f32x4*)(sc + n * 64 + cq * 4);
          f32x4 x4a = *(const f32x4*)(xc + n * 128 + cq * 8);
          f32x4 x4b = *(const f32x4*)(xc + n * 128 + cq * 8 + 4);
#pragma unroll
          for (int i = 0; i < 4; ++i) {
#pragma unroll
            for (int j = 0; j < 4; ++j) {
              ssa[i][j] += s4[i] * s4b[j];
              pa[i * 2][j] += s4[i] * x4a[j];
              pa[i * 2 + 1][j] += s4[i] * x4b[j];
            }
          }
        }
        for (int n = nq; n < 32; n += 4) csA += sc[n * 64 + kk];
      }
    }
    if (act) {
      float* sp = ss_part + ((size_t)(b * 16 + ch)) * 4096;
      float* pp = p_part + ((size_t)(b * 16 + ch)) * 8192;
#pragma unroll
      for (int i = 0; i < 4; ++i) {
        *(f32x4*)(sp + (kq * 4 + i) * 64 + cq * 4) = ssa[i];
        *(f32x4*)(pp + (kq * 4 + i) * 128 + cq * 8) = pa[i * 2];
        *(f32x4*)(pp + (kq * 4 + i) * 128 + cq * 8 + 4) = pa[i * 2 + 1];
      }
    }
    __syncthreads();
    if (act) { qc[nq * 64 + kk] = csA; }
    __syncthreads();
    if (tid < 64)
      csp[(size_t)(b * 16 + ch) * 64 + tid] =
          qc[0 * 64 + tid] + qc[1 * 64 + tid] + qc[2 * 64 + tid] + qc[3 * 64 + tid];
  }
}

// ---------------------------------------------------------------- k_reduce
__global__ __launch_bounds__(256) void k_reduce(
    const float* __restrict__ oadj_part, const float* __restrict__ ss_part,
    const float* __restrict__ p_part, float* __restrict__ oadj_raw,
    float* __restrict__ ss_sum, float* __restrict__ out_feat) {
  const int gid = blockIdx.x * 256 + threadIdx.x;
  if (gid < 32768) {
    int b = gid >> 12, e = gid & 4095;
    float s = 0.f;
    for (int t = 0; t < 64; ++t) s += oadj_part[((size_t)(b * 64 + t)) * 4096 + e];
    oadj_raw[gid] = s;
  } else if (gid < 65536) {
    int g2 = gid - 32768, b = g2 >> 12, e = g2 & 4095;
    float s = 0.f;
    for (int t = 0; t < 16; ++t) s += ss_part[((size_t)(b * 16 + t)) * 4096 + e];
    ss_sum[g2] = s;
  } else {
    int g3 = gid - 65536, b = g3 >> 13, e = g3 & 8191;
    float s = 0.f;
    for (int t = 0; t < 16; ++t) s += p_part[((size_t)(b * 16 + t)) * 8192 + e];
    const float scale = 1.0507009873554805f, alpha = 1.6732632423543772f;
    out_feat[g3] = s > 0.f ? scale * s : scale * alpha * (expf(s) - 1.f);
  }
}

// ---------------------------------------------------------------- k_finalize
// ca = rowsum(oadj_raw); 2m = sum(oadj_raw)  (softmax rows sum to 1).
__global__ __launch_bounds__(256) void k_finalize(
    const float* __restrict__ oadj_raw, const float* __restrict__ ss_sum,
    const float* __restrict__ csp, float* __restrict__ out_adj,
    float* __restrict__ loss_part) {
  __shared__ float red[256];
  __shared__ float ca[64], dvec[64], diag[64];
  const int b = blockIdx.x, t = threadIdx.x;
  const float* ob = oadj_raw + b * 4096;
  const float* ssb = ss_sum + b * 4096;

  if (t < 64) {
    const float* orow = ob + t * 64;
    float full = 0.f, nod = 0.f;
    for (int lc = 0; lc < 64; ++lc) {
      float v = orow[lc];
      full += v;
      nod += (lc != t) ? v : 0.f;
    }
    ca[t] = full;
    dvec[t] = sqrtf(nod) + 1e-15f;
    diag[t] = orow[t];
  }
  __syncthreads();

  red[t] = (t < 64) ? ca[t] : 0.f;
  __syncthreads();
  for (int o = 128; o > 0; o >>= 1) { if (t < o) red[t] += red[t + o]; __syncthreads(); }
  const float sm = red[0];
  __syncthreads();

  red[t] = (t < 64) ? (diag[t] - ca[t] * ca[t] / sm) : 0.f;
  __syncthreads();
  for (int o = 128; o > 0; o >>= 1) { if (t < o) red[t] += red[t + o]; __syncthreads(); }
  const float spectral_b = -red[0] / sm;
  __syncthreads();

  float fp = 0.f;
  for (int i = t; i < 4096; i += 256) { float v = ssb[i]; fp += v * v; }
  red[t] = fp; __syncthreads();
  for (int o = 128; o > 0; o >>= 1) { if (t < o) red[t] += red[t + o]; __syncthreads(); }
  const float fro = sqrtf(red[0]);
  __syncthreads();
  float op2 = 0.f;
  for (int i = t; i < 4096; i += 256) {
    float v = ssb[i] / fro - (((i >> 6) == (i & 63)) ? 0.125f : 0.f);
    op2 += v * v;
  }
  red[t] = op2; __syncthreads();
  for (int o = 128; o > 0; o >>= 1) { if (t < o) red[t] += red[t + o]; __syncthreads(); }
  const float ortho_b = sqrtf(red[0]);
  __syncthreads();

  float csize_k = 0.f;
  if (t < 64) {
    for (int ch = 0; ch < 16; ++ch) csize_k += csp[(size_t)(b * 16 + ch) * 64 + t];
  }
  red[t] = (t < 64) ? csize_k * csize_k : 0.f;
  __syncthreads();
  for (int o = 128; o > 0; o >>= 1) { if (t < o) red[t] += red[t + o]; __syncthreads(); }
  const float cluster_b = sqrtf(red[0]) * 8.f / 4096.f - 1.f;
  __syncthreads();

  for (int i = t; i < 4096; i += 256) {
    int kk = i >> 6, lc = i & 63;
    float v = (kk == lc) ? 0.f : ob[i] / (dvec[kk] * dvec[lc]);
    out_adj[(size_t)b * 4096 + i] = v;
  }
  if (t == 0) {
    loss_part[b * 3 + 0] = spectral_b;
    loss_part[b * 3 + 1] = ortho_b;
    loss_part[b * 3 + 2] = cluster_b;
  }
}

__global__ void k_scalars(const float* __restrict__ lp, float* __restrict__ o3) {
  if (threadIdx.x == 0) {
    float s = 0.f, o = 0.f, c = 0.f;
    for (int b = 0; b < 8; ++b) { s += lp[b * 3]; o += lp[b * 3 + 1]; c += lp[b * 3 + 2]; }
    o3[0] = s * 0.125f; o3[1] = o * 0.125f; o3[2] = c * 0.125f;
  }
}

extern "C" void kernel_launch(void* const* d_in, const int* in_sizes, int n_in,
                              void* d_out, int out_size, void* d_ws, size_t ws_size,
                              hipStream_t stream) {
  const float* x = (const float*)d_in[0];
  const float* adj = (const float*)d_in[1];
  const float* w = (const float*)d_in[2];
  const float* bias = (const float*)d_in[3];
  float* out = (float*)d_out;
  float* s_out = out;                       // [8,4096,64]
  float* out_feat = out + 2097152;          // [8,64,128]
  float* out_adj = out + 2162688;           // [8,64,64]
  float* out_sc = out + 2195456;            // 3 scalars

  char* ws = (char*)d_ws;
  _Float16* sB = (_Float16*)ws;                              // 4 MB
  float* oadj_part = (float*)(ws + (8u << 20));              // 8 MB
  float* ss_part = (float*)(ws + (16u << 20));               // 2 MB
  float* p_part = (float*)(ws + (20u << 20));                // 4 MB
  float* oadj_raw = (float*)(ws + (28u << 20) + (128u << 10));
  float* ss_sum = (float*)(ws + (28u << 20) + (256u << 10));
  float* loss_part = (float*)(ws + (28u << 20) + (384u << 10));
  float* csp = (float*)(ws + (28u << 20) + (512u << 10));    // 32 KB

  k_assign<<<dim3(512), dim3(256), 0, stream>>>(x, w, bias, s_out, sB);
  k_fused<<<dim3(640), dim3(512), 0, stream>>>(adj, sB, s_out, x, oadj_part,
                                               ss_part, p_part, csp);
  k_reduce<<<dim3(512), dim3(256), 0, stream>>>(oadj_part, ss_part, p_part,
                                                oadj_raw, ss_sum, out_feat);
  k_finalize<<<dim3(8), dim3(256), 0, stream>>>(oadj_raw, ss_sum, csp,
                                                out_adj, loss_part);
  k_scalars<<<dim3(1), dim3(64), 0, stream>>>(loss_part, out_sc);
}

// Round 13
// 171.561 us; speedup vs baseline: 3.2011x; 1.0467x over previous
//
#include <hip/hip_runtime.h>
#include <hip/hip_bf16.h>

// DMoN pooling, MI355X. B=8, N=4096, C=128, K=64.
// R13 = R8 (best measured, 172.2us) + 4-bit LDS swizzle only.
//  k_assign : s = softmax(x@W+b) via fp16-split MFMA; writes s (f32) + packed
//             S fragments (fp16 hi only) in MFMA B-layout.
//  k_fused  : heterogeneous grid 640, SEQUENTIAL (R12's interleave cost ~7us:
//             small blocks carry the same 72KB LDS footprint, displacing
//             HBM-critical big blocks with no packing gain).
//             blocks 0..511  = k_big: Y = adj @ S via T3/T4 staged pipeline
//               (3-deep LDS ring: 16KB adj + 8KB frag per step; counted
//               vmcnt(3) BEFORE s_barrier -> own stage retired, next stays in
//               flight, never 0 mid-loop). Adj source pre-XOR-swizzled 4-bit
//               (row&15)<<4, ds_reads XOR the same (conflicts 5.3M->1.1M,
//               R10-measured). Epilogue folds oadj_part = S_tile^T @ Y_tile.
//             blocks 512..639 = k_small: partials of ss = S^T S,
//               pooled = S^T X, csize = colsum(S); backfills freed slots.
//  k_reduce / k_finalize / k_scalars: reduce partials, losses, normalize.
//  deg never materialized: softmax rows sum to 1 => ca = rowsum(oadj_raw).
// All reductions deterministic (fixed-order partials, no FP atomics).
// Encoded lessons: (512,6) bounds => 40-VGPR spill (R9/R10); per-wave
// reg-frags from L2 lose to LDS-staged frags (R11: 200 vs 172).

typedef _Float16 f16x8 __attribute__((ext_vector_type(8)));
typedef float f32x4 __attribute__((ext_vector_type(4)));

#define MFMA16(a, b, c) __builtin_amdgcn_mfma_f32_16x16x32_f16((a), (b), (c), 0, 0, 0)

__device__ __forceinline__ void gld_lds16(const void* g, void* l) {
  __builtin_amdgcn_global_load_lds(
      (const __attribute__((address_space(1))) void*)g,
      (__attribute__((address_space(3))) void*)l, 16, 0, 0);
}

template <int NCHUNK>
__device__ __forceinline__ void stage_lds(const void* g, void* lbase, int tid) {
  char* ld = (char*)lbase + (tid >> 6) * 1024;   // wave-uniform base; HW adds lane*16
  const char* gs = (const char*)g + tid * 16;
#pragma unroll
  for (int p = 0; p < NCHUNK; ++p)
    gld_lds16(gs + p * 4096, ld + p * 4096);
}

// ---------------------------------------------------------------- k_assign
__global__ __launch_bounds__(256) void k_assign(
    const float* __restrict__ x, const float* __restrict__ w,
    const float* __restrict__ bias, float* __restrict__ s_out,
    _Float16* __restrict__ sB) {
  __shared__ __align__(16) _Float16 wT[2][64][136];
  __shared__ __align__(16) float sT[64][76];
  const int b = blockIdx.x & 7;
  const int it = blockIdx.x >> 3;
  const int n_base = it * 64;
  const int tid = threadIdx.x;

  for (int idx = tid; idx < 8192; idx += 256) {
    int c = idx >> 6, k = idx & 63;
    float v = w[idx];
    _Float16 h = (_Float16)v;
    wT[0][k][c] = h;
    wT[1][k][c] = (_Float16)(v - (float)h);
  }
  const int l = tid & 63, wv = tid >> 6;
  const int l15 = l & 15, g = l >> 4;
  float bv[4];
#pragma unroll
  for (int ct = 0; ct < 4; ++ct) bv[ct] = bias[ct * 16 + l15];
  __syncthreads();

  f32x4 acc[4];
#pragma unroll
  for (int ct = 0; ct < 4; ++ct) acc[ct] = (f32x4){bv[ct], bv[ct], bv[ct], bv[ct]};

  const float* xrow = x + ((size_t)(b * 4096 + n_base + wv * 16 + l15)) * 128;
#pragma unroll
  for (int cs = 0; cs < 4; ++cs) {
    const int c0 = cs * 32;
    f32x4 r0 = *(const f32x4*)(xrow + c0 + 8 * g);
    f32x4 r1 = *(const f32x4*)(xrow + c0 + 8 * g + 4);
    f16x8 ah, al;
#pragma unroll
    for (int j = 0; j < 4; ++j) {
      float v0 = r0[j]; _Float16 h0 = (_Float16)v0;
      ah[j] = h0; al[j] = (_Float16)(v0 - (float)h0);
      float v1 = r1[j]; _Float16 h1 = (_Float16)v1;
      ah[4 + j] = h1; al[4 + j] = (_Float16)(v1 - (float)h1);
    }
#pragma unroll
    for (int ct = 0; ct < 4; ++ct) {
      f16x8 bh = *(const f16x8*)&wT[0][ct * 16 + l15][c0 + 8 * g];
      f16x8 bl = *(const f16x8*)&wT[1][ct * 16 + l15][c0 + 8 * g];
      acc[ct] = MFMA16(ah, bh, acc[ct]);
      acc[ct] = MFMA16(al, bh, acc[ct]);
      acc[ct] = MFMA16(ah, bl, acc[ct]);
    }
  }

#pragma unroll
  for (int r = 0; r < 4; ++r) {
    float m = fmaxf(fmaxf(acc[0][r], acc[1][r]), fmaxf(acc[2][r], acc[3][r]));
#pragma unroll
    for (int off = 1; off < 16; off <<= 1) m = fmaxf(m, __shfl_xor(m, off, 64));
    float e[4], sum = 0.f;
#pragma unroll
    for (int ct = 0; ct < 4; ++ct) { e[ct] = __expf(acc[ct][r] - m); sum += e[ct]; }
#pragma unroll
    for (int off = 1; off < 16; off <<= 1) sum += __shfl_xor(sum, off, 64);
    float inv = 1.0f / sum;
#pragma unroll
    for (int ct = 0; ct < 4; ++ct) acc[ct][r] = e[ct] * inv;
  }

  const int row_l = wv * 16 + 4 * g;
  float* srow = s_out + ((size_t)(b * 4096 + n_base)) * 64;
#pragma unroll
  for (int r = 0; r < 4; ++r)
#pragma unroll
    for (int ct = 0; ct < 4; ++ct) {
      srow[(size_t)(row_l + r) * 64 + ct * 16 + l15] = acc[ct][r];
      sT[ct * 16 + l15][row_l + r] = acc[ct][r];
    }
  __syncthreads();

  // repack to B-fragment layout (hi only): [ks][ct][lane][8] fp16
  _Float16* dst = sB + (size_t)(b * 64 + it) * 4096;
#pragma unroll
  for (int p = 0; p < 2; ++p) {
    int slot = tid + 256 * p;                 // 0..511
    int ks = slot >> 8, ct = (slot >> 6) & 3, ln = slot & 63;
    int col = ct * 16 + (ln & 15);
    int row0 = ks * 32 + 8 * (ln >> 4);
    f16x8 o;
#pragma unroll
    for (int j = 0; j < 8; ++j) o[j] = (_Float16)sT[col][row0 + j];
    *(f16x8*)(dst + slot * 8) = o;
  }
}

// ---------------------------------------------------------------- k_fused
// blocks 0..511: k_big body. blocks 512..639: k_small body (256 active thr).
__global__ __launch_bounds__(512, 4) void k_fused(
    const float* __restrict__ adj, const _Float16* __restrict__ sB,
    const float* __restrict__ s_out, const float* __restrict__ x,
    float* __restrict__ oadj_part, float* __restrict__ ss_part,
    float* __restrict__ p_part, float* __restrict__ csp) {
  __shared__ __align__(16) char pool[73728];   // big: 3*16K adj + 3*8K frag
  const int tid = threadIdx.x;

  if (blockIdx.x < 512) {
    // ------------------------------ k_big body (R8 structure, 4-bit swizzle)
    const int b = blockIdx.x & 7;
    const int nt = blockIdx.x >> 3;
    const int n_base = nt * 64;
    const int l = tid & 63, w = tid >> 6;
    const int rt = w & 3, ch = w >> 2;
    const int g = l >> 4;

    const char* sBb = (const char*)(sB + (size_t)b * 64 * 4096);
    // 4-bit pre-swizzled source: col-byte ^= (row&15)<<4 (bits 4..7).
    const char* asrc = (const char*)adj +
        ((size_t)(b * 4096 + n_base + (tid >> 4)) * 4096) * 4 +
        (((tid & 15) * 16) ^ (((tid >> 4) & 15) << 4));
    const size_t CH1 = (size_t)32 * 16384;
    const char* fsrc = sBb + tid * 16;

    auto stage = [&](int s, int buf) {
      char* ab = pool + buf * 16384 + w * 1024;
      const char* a0 = asrc + (size_t)s * 256;
      gld_lds16(a0, ab);
      gld_lds16(a0 + CH1, ab + 8192);
      gld_lds16(fsrc + (size_t)s * 8192, pool + 49152 + buf * 8192 + w * 1024);
    };

    stage(0, 0);
    stage(1, 1);

    const int rowbase = (rt * 16 + (l & 15)) * 256;
    const int swz = (l & 15) << 4;
    int innerX[4];
#pragma unroll
    for (int ks = 0; ks < 2; ++ks)
#pragma unroll
      for (int part = 0; part < 2; ++part)
        innerX[ks * 2 + part] = (ks * 128 + g * 32 + part * 16) ^ swz;

    f32x4 acc[2] = {};
    int buf = 0;
    for (int s = 0; s < 64; ++s) {
      // counted wait BEFORE barrier: retire own stage(s) [3 ops], leave
      // stage(s+1) [3 ops] in flight; never vmcnt(0) mid-loop.
      if (s == 63) asm volatile("s_waitcnt vmcnt(0)" ::: "memory");
      else         asm volatile("s_waitcnt vmcnt(3)" ::: "memory");
      __builtin_amdgcn_sched_barrier(0);
      __builtin_amdgcn_s_barrier();
      if (s < 62) {
        int nb = buf + 2; if (nb >= 3) nb -= 3;
        stage(s + 2, nb);
      }
      const char* ab = pool + buf * 16384;
      const char* fbb = pool + 49152 + buf * 8192;
#pragma unroll
      for (int ks = 0; ks < 2; ++ks) {
        f32x4 lo = *(const f32x4*)(ab + rowbase + innerX[ks * 2]);
        f32x4 hi = *(const f32x4*)(ab + rowbase + innerX[ks * 2 + 1]);
        f16x8 af;
#pragma unroll
        for (int j = 0; j < 4; ++j) {
          af[j] = (_Float16)lo[j];
          af[4 + j] = (_Float16)hi[j];
        }
        f16x8 b0 = *(const f16x8*)(fbb + (ks * 4 + ch * 2 + 0) * 1024 + l * 16);
        f16x8 b1 = *(const f16x8*)(fbb + (ks * 4 + ch * 2 + 1) * 1024 + l * 16);
        acc[0] = MFMA16(af, b0, acc[0]);
        acc[1] = MFMA16(af, b1, acc[1]);
      }
      buf = (buf == 2) ? 0 : buf + 1;
    }

    // epilogue: stage s tile (f32) into dead ring space, Y -> LDS, fold.
    {
      const char* ssrc =
          (const char*)(s_out + (size_t)(b * 4096 + n_base) * 64) + tid * 16;
      gld_lds16(ssrc, pool + 16384 + w * 1024);
      gld_lds16(ssrc + 8192, pool + 16384 + w * 1024 + 8192);
    }
    __syncthreads();   // drains vmcnt: s staged; ring dead

    float* Yl = (float*)pool;
    float* sl = (float*)(pool + 16384);
#pragma unroll
    for (int r = 0; r < 4; ++r) {
      Yl[(rt * 16 + (l >> 4) * 4 + r) * 64 + (ch * 2 + 0) * 16 + (l & 15)] = acc[0][r];
      Yl[(rt * 16 + (l >> 4) * 4 + r) * 64 + (ch * 2 + 1) * 16 + (l & 15)] = acc[1][r];
    }
    __syncthreads();

    const int kq = tid >> 4, lq = tid & 15;
    f32x4 a2a = {}, a2b = {};
    for (int r = 0; r < 64; ++r) {
      float sA = sl[r * 64 + kq];
      float sC = sl[r * 64 + 32 + kq];
      f32x4 y4 = *(const f32x4*)(Yl + r * 64 + lq * 4);
#pragma unroll
      for (int j = 0; j < 4; ++j) { a2a[j] += sA * y4[j]; a2b[j] += sC * y4[j]; }
    }
    float* op = oadj_part + ((size_t)(b * 64 + nt)) * 4096;
    *(f32x4*)(op + kq * 64 + lq * 4) = a2a;
    *(f32x4*)(op + (kq + 32) * 64 + lq * 4) = a2b;
  } else {
    // ------------------------------ k_small body (256 active threads)
    const int bid2 = blockIdx.x - 512;      // 0..127
    const int b = bid2 & 7;
    const int ch = bid2 >> 3;               // 16 chunks of 256 rows
    const bool act = tid < 256;
    float* sc = (float*)pool;               // 8 KB
    float* xc = (float*)(pool + 8192);      // 16 KB
    float* qc = (float*)(pool + 8192 + 16384);  // 4*64 floats
    const int kq = tid >> 4, cq = tid & 15;
    const int kk = tid & 63, nq = tid >> 6;
    f32x4 ssa[4] = {};
    f32x4 pa[8] = {};
    float csA = 0.f;
    for (int sub = 0; sub < 8; ++sub) {
      if (sub) __syncthreads();
      const int nb = ch * 256 + sub * 32;
      if (act) {
        stage_lds<2>(s_out + ((size_t)(b * 4096 + nb)) * 64, sc, tid);
        stage_lds<4>(x + ((size_t)(b * 4096 + nb)) * 128, xc, tid);
      }
      __syncthreads();
      if (act) {
        for (int n = 0; n < 32; ++n) {
          f32x4 s4 = *(const f32x4*)(sc + n * 64 + kq * 4);
          f32x4 s4b = *(const f32x4*)(sc + n * 64 + cq * 4);
          f32x4 x4a = *(const f32x4*)(xc + n * 128 + cq * 8);
          f32x4 x4b = *(const f32x4*)(xc + n * 128 + cq * 8 + 4);
#pragma unroll
          for (int i = 0; i < 4; ++i) {
#pragma unroll
            for (int j = 0; j < 4; ++j) {
              ssa[i][j] += s4[i] * s4b[j];
              pa[i * 2][j] += s4[i] * x4a[j];
              pa[i * 2 + 1][j] += s4[i] * x4b[j];
            }
          }
        }
        for (int n = nq; n < 32; n += 4) csA += sc[n * 64 + kk];
      }
    }
    if (act) {
      float* sp = ss_part + ((size_t)(b * 16 + ch)) * 4096;
      float* pp = p_part + ((size_t)(b * 16 + ch)) * 8192;
#pragma unroll
      for (int i = 0; i < 4; ++i) {
        *(f32x4*)(sp + (kq * 4 + i) * 64 + cq * 4) = ssa[i];
        *(f32x4*)(pp + (kq * 4 + i) * 128 + cq * 8) = pa[i * 2];
        *(f32x4*)(pp + (kq * 4 + i) * 128 + cq * 8 + 4) = pa[i * 2 + 1];
      }
    }
    __syncthreads();
    if (act) { qc[nq * 64 + kk] = csA; }
    __syncthreads();
    if (tid < 64)
      csp[(size_t)(b * 16 + ch) * 64 + tid] =
          qc[0 * 64 + tid] + qc[1 * 64 + tid] + qc[2 * 64 + tid] + qc[3 * 64 + tid];
  }
}

// ---------------------------------------------------------------- k_reduce
__global__ __launch_bounds__(256) void k_reduce(
    const float* __restrict__ oadj_part, const float* __restrict__ ss_part,
    const float* __restrict__ p_part, float* __restrict__ oadj_raw,
    float* __restrict__ ss_sum, float* __restrict__ out_feat) {
  const int gid = blockIdx.x * 256 + threadIdx.x;
  if (gid < 32768) {
    int b = gid >> 12, e = gid & 4095;
    float s = 0.f;
    for (int t = 0; t < 64; ++t) s += oadj_part[((size_t)(b * 64 + t)) * 4096 + e];
    oadj_raw[gid] = s;
  } else if (gid < 65536) {
    int g2 = gid - 32768, b = g2 >> 12, e = g2 & 4095;
    float s = 0.f;
    for (int t = 0; t < 16; ++t) s += ss_part[((size_t)(b * 16 + t)) * 4096 + e];
    ss_sum[g2] = s;
  } else {
    int g3 = gid - 65536, b = g3 >> 13, e = g3 & 8191;
    float s = 0.f;
    for (int t = 0; t < 16; ++t) s += p_part[((size_t)(b * 16 + t)) * 8192 + e];
    const float scale = 1.0507009873554805f, alpha = 1.6732632423543772f;
    out_feat[g3] = s > 0.f ? scale * s : scale * alpha * (expf(s) - 1.f);
  }
}

// ---------------------------------------------------------------- k_finalize
// ca = rowsum(oadj_raw); 2m = sum(oadj_raw)  (softmax rows sum to 1).
__global__ __launch_bounds__(256) void k_finalize(
    const float* __restrict__ oadj_raw, const float* __restrict__ ss_sum,
    const float* __restrict__ csp, float* __restrict__ out_adj,
    float* __restrict__ loss_part) {
  __shared__ float red[256];
  __shared__ float ca[64], dvec[64], diag[64];
  const int b = blockIdx.x, t = threadIdx.x;
  const float* ob = oadj_raw + b * 4096;
  const float* ssb = ss_sum + b * 4096;

  if (t < 64) {
    const float* orow = ob + t * 64;
    float full = 0.f, nod = 0.f;
    for (int lc = 0; lc < 64; ++lc) {
      float v = orow[lc];
      full += v;
      nod += (lc != t) ? v : 0.f;
    }
    ca[t] = full;
    dvec[t] = sqrtf(nod) + 1e-15f;
    diag[t] = orow[t];
  }
  __syncthreads();

  red[t] = (t < 64) ? ca[t] : 0.f;
  __syncthreads();
  for (int o = 128; o > 0; o >>= 1) { if (t < o) red[t] += red[t + o]; __syncthreads(); }
  const float sm = red[0];
  __syncthreads();

  red[t] = (t < 64) ? (diag[t] - ca[t] * ca[t] / sm) : 0.f;
  __syncthreads();
  for (int o = 128; o > 0; o >>= 1) { if (t < o) red[t] += red[t + o]; __syncthreads(); }
  const float spectral_b = -red[0] / sm;
  __syncthreads();

  float fp = 0.f;
  for (int i = t; i < 4096; i += 256) { float v = ssb[i]; fp += v * v; }
  red[t] = fp; __syncthreads();
  for (int o = 128; o > 0; o >>= 1) { if (t < o) red[t] += red[t + o]; __syncthreads(); }
  const float fro = sqrtf(red[0]);
  __syncthreads();
  float op2 = 0.f;
  for (int i = t; i < 4096; i += 256) {
    float v = ssb[i] / fro - (((i >> 6) == (i & 63)) ? 0.125f : 0.f);
    op2 += v * v;
  }
  red[t] = op2; __syncthreads();
  for (int o = 128; o > 0; o >>= 1) { if (t < o) red[t] += red[t + o]; __syncthreads(); }
  const float ortho_b = sqrtf(red[0]);
  __syncthreads();

  float csize_k = 0.f;
  if (t < 64) {
    for (int ch = 0; ch < 16; ++ch) csize_k += csp[(size_t)(b * 16 + ch) * 64 + t];
  }
  red[t] = (t < 64) ? csize_k * csize_k : 0.f;
  __syncthreads();
  for (int o = 128; o > 0; o >>= 1) { if (t < o) red[t] += red[t + o]; __syncthreads(); }
  const float cluster_b = sqrtf(red[0]) * 8.f / 4096.f - 1.f;
  __syncthreads();

  for (int i = t; i < 4096; i += 256) {
    int kk = i >> 6, lc = i & 63;
    float v = (kk == lc) ? 0.f : ob[i] / (dvec[kk] * dvec[lc]);
    out_adj[(size_t)b * 4096 + i] = v;
  }
  if (t == 0) {
    loss_part[b * 3 + 0] = spectral_b;
    loss_part[b * 3 + 1] = ortho_b;
    loss_part[b * 3 + 2] = cluster_b;
  }
}

__global__ void k_scalars(const float* __restrict__ lp, float* __restrict__ o3) {
  if (threadIdx.x == 0) {
    float s = 0.f, o = 0.f, c = 0.f;
    for (int b = 0; b < 8; ++b) { s += lp[b * 3]; o += lp[b * 3 + 1]; c += lp[b * 3 + 2]; }
    o3[0] = s * 0.125f; o3[1] = o * 0.125f; o3[2] = c * 0.125f;
  }
}

extern "C" void kernel_launch(void* const* d_in, const int* in_sizes, int n_in,
                              void* d_out, int out_size, void* d_ws, size_t ws_size,
                              hipStream_t stream) {
  const float* x = (const float*)d_in[0];
  const float* adj = (const float*)d_in[1];
  const float* w = (const float*)d_in[2];
  const float* bias = (const float*)d_in[3];
  float* out = (float*)d_out;
  float* s_out = out;                       // [8,4096,64]
  float* out_feat = out + 2097152;          // [8,64,128]
  float* out_adj = out + 2162688;           // [8,64,64]
  float* out_sc = out + 2195456;            // 3 scalars

  char* ws = (char*)d_ws;
  _Float16* sB = (_Float16*)ws;                              // 4 MB
  float* oadj_part = (float*)(ws + (8u << 20));              // 8 MB
  float* ss_part = (float*)(ws + (16u << 20));               // 2 MB
  float* p_part = (float*)(ws + (20u << 20));                // 4 MB
  float* oadj_raw = (float*)(ws + (28u << 20) + (128u << 10));
  float* ss_sum = (float*)(ws + (28u << 20) + (256u << 10));
  float* loss_part = (float*)(ws + (28u << 20) + (384u << 10));
  float* csp = (float*)(ws + (28u << 20) + (512u << 10));    // 32 KB

  k_assign<<<dim3(512), dim3(256), 0, stream>>>(x, w, bias, s_out, sB);
  k_fused<<<dim3(640), dim3(512), 0, stream>>>(adj, sB, s_out, x, oadj_part,
                                               ss_part, p_part, csp);
  k_reduce<<<dim3(512), dim3(256), 0, stream>>>(oadj_part, ss_part, p_part,
                                                oadj_raw, ss_sum, out_feat);
  k_finalize<<<dim3(8), dim3(256), 0, stream>>>(oadj_raw, ss_sum, csp,
                                                out_adj, loss_part);
  k_scalars<<<dim3(1), dim3(64), 0, stream>>>(loss_part, out_sc);
}